// Round 11
// baseline (139.319 us; speedup 1.0000x reference)
//
#include <hip/hip_runtime.h>
#include <math.h>

typedef _Float16 f16;
typedef f16 half8 __attribute__((ext_vector_type(8)));
typedef float f32x4 __attribute__((ext_vector_type(4)));

// Problem sizes: B=4, T=2048, G=8, D=128, V=1024
#define BT 8192
#define NG 8
#define ND 128
#define NV 1024
#define MARGIN 0.02f
#define BM 64        // tokens per block
#define BN 64        // codes per tile
#define NT 16        // code tiles

// d_out layout (float32): ids[65536] | quantized_st[8388608] | 3 losses
#define OUT_IDS 0
#define OUT_Q   65536
#define OUT_L   (65536 + 8388608)

// ws float offsets (~4.8 MB)
#define OFF_C2A   0                        // c2 [v*8+g] (recheck)     (8192)
#define OFF_C2B   8192                     // c2 [g*NV+v] (gemm)       (8192)
#define OFF_IDS   16384                    // ids int                  (65536)
#define OFF_LOSS  81920                    // per-token loss           (8192)
#define OFF_CNT   90112                    // flag count               (8)
#define OFF_FLAGS 90120                    // flag list                (65536)
#define OFF_CBH   155656                   // cbh fp16 swizzled stream (524288 fl)
#define OFF_CBL   (OFF_CBH + 524288)       // cbl fp16 swizzled stream (524288 fl)

// ---------------------------------------------------------------------------
// async global->LDS, 16B per lane (linear dest, pre-swizzled source)
// ---------------------------------------------------------------------------
__device__ __forceinline__ void gll16(const f16* g, f16* l) {
    __builtin_amdgcn_global_load_lds(
        (const __attribute__((address_space(1))) unsigned int*)g,
        (__attribute__((address_space(3))) unsigned int*)l, 16, 0, 0);
}

// ---------------------------------------------------------------------------
// prep: c2 (both layouts, R1-exact pairwise-8 order) + fp16 h/l split of the
// codebook written as PRE-SWIZZLED g-blocked 64-row tile chunks:
// stream[(g*16+cn)*8192 + rl*128 + j*8 + e] = cb[v=cn*64+rl][(j^(rl&7))*8+e]
// so a linear global_load_lds fill yields the XOR-swizzled LDS tile.
// ---------------------------------------------------------------------------
__global__ __launch_bounds__(256) void prep_kernel(
    const float* __restrict__ cb, f16* __restrict__ cbh, f16* __restrict__ cbl,
    float* __restrict__ c2a, float* __restrict__ c2b, int* __restrict__ cnt) {
    int idx = blockIdx.x * 256 + threadIdx.x;   // v*8+g
    if (idx == 0) *cnt = 0;
    int v = idx >> 3, g = idx & 7;
    const float* row = cb + (size_t)idx * ND;

    float r[8];
#pragma unroll
    for (int j = 0; j < 8; ++j) r[j] = 0.0f;
#pragma unroll
    for (int k = 0; k < 16; ++k)
#pragma unroll
        for (int j = 0; j < 8; ++j) {
            float c = row[k * 8 + j];
            r[j] = __fadd_rn(r[j], __fmul_rn(c, c));
        }
    float s = __fadd_rn(
        __fadd_rn(__fadd_rn(r[0], r[1]), __fadd_rn(r[2], r[3])),
        __fadd_rn(__fadd_rn(r[4], r[5]), __fadd_rn(r[6], r[7])));
    c2a[idx] = s;
    c2b[g * NV + v] = s;

    int cn = v >> 6, rl = v & 63;
    size_t base = ((size_t)(g * 16 + cn)) * 8192 + rl * 128;
#pragma unroll
    for (int j = 0; j < 16; ++j) {
        int js = (j ^ (rl & 7)) * 8;
        half8 h, l;
#pragma unroll
        for (int e = 0; e < 8; ++e) {
            float vv = row[js + e];
            f16 hh = (f16)vv;
            h[e] = hh;
            l[e] = (f16)(vv - (float)hh);
        }
        *(half8*)(cbh + base + j * 8) = h;
        *(half8*)(cbl + base + j * 8) = l;
    }
}

// ---------------------------------------------------------------------------
// MFMA distance GEMM, TALL waves + counted-wait pipeline.
// Block = 64 tokens x one g; 4 waves each own a DISJOINT 16-code quarter and
// cover ALL 64 tokens (ti=4) -> zero LDS-read redundancy (96 FLOP/B).
// B: 16 tiles of 64 codes, double-buffered (2x32KB), filled by global_load_lds
// from the pre-swizzled stream. Sync per tile (m201 idiom):
//   asm vmcnt(0)  [waits ONLY tile t's own loads, which flew under compute t-1]
//   raw s_barrier + sched_barrier(0)
//   issue tile t+1 DMA   [stays in flight across the next barrier]
//   compute tile t
// Write-after-read safe: issue of t+1 into buf^1 follows the barrier that
// closes all reads of tile t-1. s = xh*ch + xh*cl + xl*ch, identical per-acc
// chain order to R10 -> distances bitwise-equal; d'=c2-2s (x2 cancels).
// Per-thread running exact top-2; flag iff d2-d1<MARGIN -> exact recheck.
// ---------------------------------------------------------------------------
__global__ __launch_bounds__(256, 2) void mfma_gemm(
    const float* __restrict__ x, const f16* __restrict__ cbh,
    const f16* __restrict__ cbl, const float* __restrict__ c2b,
    const int* __restrict__ pad, int* __restrict__ ws_ids,
    float* __restrict__ out_ids, int* __restrict__ cnt,
    int* __restrict__ flags) {
    __shared__ __align__(16) f16 Bh[2][BN * ND];   // 2 x 16 KB
    __shared__ __align__(16) f16 Bl[2][BN * ND];   // 2 x 16 KB
    __shared__ __align__(16) float c2s[NV];        // 4 KB

    const int tid = threadIdx.x;
    const int b = blockIdx.x;
    const int g = b & 7;
    const int tok0 = (b >> 3) * BM;
    const int lane = tid & 63;
    const int w = tid >> 6;                  // code quarter
    const int l15 = lane & 15, l4 = lane >> 4;
    const int rw = w * 16 + l15;             // this lane's code row in tile

    // ---- prologue ----
    // c2 -> LDS (ds_write; load's waitcnt happens before any DMA is issued)
    ((float4*)c2s)[tid] = ((const float4*)(c2b + (size_t)g * NV))[tid];
    // issue tile 0 DMA (8 loads), stays in flight under the A-load/split
    {
        const f16* sh = cbh + ((size_t)(g * 16 + 0)) * 8192;
        const f16* sl = cbl + ((size_t)(g * 16 + 0)) * 8192;
#pragma unroll
        for (int it = 0; it < 4; ++it) {
            int off = it * 2048 + tid * 8;
            gll16(sh + off, &Bh[0][off]);
            gll16(sl + off, &Bl[0][off]);
        }
    }
    // A: 64 tokens per wave (ti=4), fp32 read once, fp16 h/l split in regs
    half8 ah[4][4], al[4][4];   // [kk][ti]
#pragma unroll
    for (int kk = 0; kk < 4; ++kk)
#pragma unroll
        for (int ti = 0; ti < 4; ++ti) {
            const float* ap = x + ((size_t)(tok0 + ti * 16 + l15) * NG + g) * ND
                              + kk * 32 + l4 * 8;
            float4 p0 = *(const float4*)ap, p1 = *(const float4*)(ap + 4);
            float v[8] = {p0.x, p0.y, p0.z, p0.w, p1.x, p1.y, p1.z, p1.w};
            half8 h, l;
#pragma unroll
            for (int j = 0; j < 8; ++j) {
                f16 hh = (f16)v[j];
                h[j] = hh;
                l[j] = (f16)(v[j] - (float)hh);
            }
            ah[kk][ti] = h;
            al[kk][ti] = l;
        }

    float d1s[4][4], d2s[4][4];
    int ids_[4][4];
#pragma unroll
    for (int ti = 0; ti < 4; ++ti)
#pragma unroll
        for (int r = 0; r < 4; ++r) {
            d1s[ti][r] = INFINITY;
            d2s[ti][r] = INFINITY;
            ids_[ti][r] = 0;
        }

    asm volatile("s_waitcnt lgkmcnt(0)" ::: "memory");  // c2s ds_write visible

    int buf = 0;
#pragma unroll 1
    for (int t = 0; t < NT; ++t) {
        // wait ONLY our own tile-t loads (they flew under compute of t-1)
        asm volatile("s_waitcnt vmcnt(0)" ::: "memory");
        __builtin_amdgcn_s_barrier();          // all waves: tile t fully in LDS
        __builtin_amdgcn_sched_barrier(0);     // pin: nothing hoists above

        // issue tile t+1 (crosses the next barrier un-drained)
        if (t + 1 < NT) {
            const f16* sh = cbh + ((size_t)(g * 16 + t + 1)) * 8192;
            const f16* sl = cbl + ((size_t)(g * 16 + t + 1)) * 8192;
#pragma unroll
            for (int it = 0; it < 4; ++it) {
                int off = it * 2048 + tid * 8;
                gll16(sh + off, &Bh[buf ^ 1][off]);
                gll16(sl + off, &Bl[buf ^ 1][off]);
            }
        }

        // compute tile t
        const int cbase = t * BN + rw;
        f32x4 acc[4];
#pragma unroll
        for (int ti = 0; ti < 4; ++ti) acc[ti] = (f32x4){0.f, 0.f, 0.f, 0.f};

#pragma unroll
        for (int kk = 0; kk < 4; ++kk) {
            int off = rw * 128 + (((kk * 4 + l4) ^ (rw & 7)) << 3);
            half8 bh = *(const half8*)(&Bh[buf][off]);
            half8 bl = *(const half8*)(&Bl[buf][off]);
#pragma unroll
            for (int ti = 0; ti < 4; ++ti)
                acc[ti] = __builtin_amdgcn_mfma_f32_16x16x32_f16(
                    ah[kk][ti], bh, acc[ti], 0, 0, 0);
#pragma unroll
            for (int ti = 0; ti < 4; ++ti)
                acc[ti] = __builtin_amdgcn_mfma_f32_16x16x32_f16(
                    ah[kk][ti], bl, acc[ti], 0, 0, 0);
#pragma unroll
            for (int ti = 0; ti < 4; ++ti)
                acc[ti] = __builtin_amdgcn_mfma_f32_16x16x32_f16(
                    al[kk][ti], bh, acc[ti], 0, 0, 0);
        }

        // epilogue: d' = c2 - 2s; per-thread running exact top-2
        float c2v = c2s[cbase];
#pragma unroll
        for (int ti = 0; ti < 4; ++ti)
#pragma unroll
            for (int r = 0; r < 4; ++r) {
                float dv = fmaf(-2.0f, acc[ti][r], c2v);
                if (dv < d1s[ti][r]) {
                    d2s[ti][r] = d1s[ti][r];
                    d1s[ti][r] = dv;
                    ids_[ti][r] = cbase;
                } else {
                    d2s[ti][r] = fminf(d2s[ti][r], dv);
                }
            }
        buf ^= 1;
    }

    // final merge: over l15 (this wave's 16 codes), then across waves via LDS
    __syncthreads();
    float4* red = (float4*)&Bh[0][0];   // 4 waves x 64 tokens x 16B = 4 KB
#pragma unroll
    for (int ti = 0; ti < 4; ++ti)
#pragma unroll
        for (int r = 0; r < 4; ++r) {
            float d1 = d1s[ti][r], d2 = d2s[ti][r];
            int id = ids_[ti][r];
#pragma unroll
            for (int m = 1; m < 16; m <<= 1) {
                float od1 = __shfl_xor(d1, m);
                float od2 = __shfl_xor(d2, m);
                int oid = __shfl_xor(id, m);
                if (od1 < d1) { d2 = fminf(d1, od2); d1 = od1; id = oid; }
                else d2 = fminf(d2, fminf(od1, od2));
            }
            if (l15 == 0)
                red[w * BM + ti * 16 + l4 * 4 + r] =
                    make_float4(d1, __int_as_float(id), d2, 0.f);
        }
    __syncthreads();

    if (tid < BM) {
        float4 a = red[tid];
        float d1 = a.x, d2 = a.z;
        int id = __float_as_int(a.y);
#pragma unroll
        for (int ww = 1; ww < 4; ++ww) {
            float4 c = red[ww * BM + tid];
            if (c.x < d1) { d2 = fminf(d1, c.z); d1 = c.x; id = __float_as_int(c.y); }
            else d2 = fminf(d2, fminf(c.x, c.z));
        }
        int tok = tok0 + tid;
        int idx = tok * NG + g;
        ws_ids[idx] = id;
        out_ids[idx] = pad[tok] ? -1.0f : (float)id;
        if (d2 - d1 < MARGIN) {
            int pos = atomicAdd(cnt, 1);
            flags[pos] = idx;
        }
    }
}

// ---------------------------------------------------------------------------
// exact fp32 recheck, BLOCK per flag: 256 threads, 4 codes/thread (ILP 4),
// x row staged in LDS (broadcast reads). R1-identical per-code arithmetic;
// index tie-break reduce == first-occurrence argmin.
// ---------------------------------------------------------------------------
__global__ __launch_bounds__(256) void recheck(
    const float* __restrict__ x, const int* __restrict__ pad,
    const float* __restrict__ cb, const float* __restrict__ c2w,
    const int* __restrict__ cnt, const int* __restrict__ flags,
    int* __restrict__ ws_ids, float* __restrict__ out_ids) {
    __shared__ __align__(16) float xs[ND];
    __shared__ float2 redw[4];
    const int tid = threadIdx.x;
    const int lane = tid & 63;
    const int w = tid >> 6;
    const int n_f = cnt[0];

    for (int f = blockIdx.x; f < n_f; f += gridDim.x) {
        int idx = flags[f];
        int g = idx & 7;
        __syncthreads();   // previous iteration's reads done
        if (tid < 32)
            ((float4*)xs)[tid] = ((const float4*)(x + (size_t)idx * ND))[tid];
        __syncthreads();

        // exact x2 (R1 pairwise-8 order), redundant per thread (broadcast)
        float rr[8];
#pragma unroll
        for (int j = 0; j < 8; ++j) rr[j] = 0.0f;
#pragma unroll
        for (int i = 0; i < 32; ++i) {
            float4 v = ((const float4*)xs)[i];
            int j0 = (i * 4) & 7;
            rr[j0 + 0] = __fadd_rn(rr[j0 + 0], __fmul_rn(v.x, v.x));
            rr[j0 + 1] = __fadd_rn(rr[j0 + 1], __fmul_rn(v.y, v.y));
            rr[j0 + 2] = __fadd_rn(rr[j0 + 2], __fmul_rn(v.z, v.z));
            rr[j0 + 3] = __fadd_rn(rr[j0 + 3], __fmul_rn(v.w, v.w));
        }
        float x2v = __fadd_rn(
            __fadd_rn(__fadd_rn(rr[0], rr[1]), __fadd_rn(rr[2], rr[3])),
            __fadd_rn(__fadd_rn(rr[4], rr[5]), __fadd_rn(rr[6], rr[7])));

        // 4 codes per thread, independent chains
        float best = INFINITY;
        int bid = 0x7FFFFFFF;
        float s0 = 0.f, s1 = 0.f, s2 = 0.f, s3 = 0.f;
#pragma unroll
        for (int i = 0; i < 32; ++i) {
            float4 a = ((const float4*)xs)[i];
            float4 q0 = ((const float4*)(cb + ((size_t)(tid) * NG + g) * ND))[i];
            float4 q1 = ((const float4*)(cb + ((size_t)(tid + 256) * NG + g) * ND))[i];
            float4 q2 = ((const float4*)(cb + ((size_t)(tid + 512) * NG + g) * ND))[i];
            float4 q3 = ((const float4*)(cb + ((size_t)(tid + 768) * NG + g) * ND))[i];
            s0 = fmaf(a.x, q0.x, s0); s0 = fmaf(a.y, q0.y, s0);
            s0 = fmaf(a.z, q0.z, s0); s0 = fmaf(a.w, q0.w, s0);
            s1 = fmaf(a.x, q1.x, s1); s1 = fmaf(a.y, q1.y, s1);
            s1 = fmaf(a.z, q1.z, s1); s1 = fmaf(a.w, q1.w, s1);
            s2 = fmaf(a.x, q2.x, s2); s2 = fmaf(a.y, q2.y, s2);
            s2 = fmaf(a.z, q2.z, s2); s2 = fmaf(a.w, q2.w, s2);
            s3 = fmaf(a.x, q3.x, s3); s3 = fmaf(a.y, q3.y, s3);
            s3 = fmaf(a.z, q3.z, s3); s3 = fmaf(a.w, q3.w, s3);
        }
        float dd[4] = {s0, s1, s2, s3};
#pragma unroll
        for (int jj = 0; jj < 4; ++jj) {
            int c = tid + 256 * jj;
            float d = __fadd_rn(__fsub_rn(x2v, __fmul_rn(2.0f, dd[jj])),
                                c2w[(size_t)c * NG + g]);
            if (d < best || (d == best && c < bid)) { best = d; bid = c; }
        }
#pragma unroll
        for (int m = 1; m < 64; m <<= 1) {
            float od = __shfl_xor(best, m);
            int ob = __shfl_xor(bid, m);
            if (od < best || (od == best && ob < bid)) { best = od; bid = ob; }
        }
        if (lane == 0) redw[w] = make_float2(best, __int_as_float(bid));
        __syncthreads();
        if (tid == 0) {
            float b2 = redw[0].x;
            int i2 = __float_as_int(redw[0].y);
#pragma unroll
            for (int ww = 1; ww < 4; ++ww) {
                float ob = redw[ww].x;
                int oi = __float_as_int(redw[ww].y);
                if (ob < b2 || (ob == b2 && oi < i2)) { b2 = ob; i2 = oi; }
            }
            ws_ids[idx] = i2;
            out_ids[idx] = pad[idx >> 3] ? -1.0f : (float)i2;
        }
    }
}

// ---------------------------------------------------------------------------
// gather quantized (masked), write quantized_st, per-token loss partial
// ---------------------------------------------------------------------------
__global__ __launch_bounds__(256) void gather_kernel(
    const float* __restrict__ x, const int* __restrict__ pad,
    const float* __restrict__ cb, const int* __restrict__ ws_ids,
    float* __restrict__ out_q, float* __restrict__ ws_loss) {
    const int n = blockIdx.x;
    const int tid = threadIdx.x;
    const int g = tid >> 5;
    const int d4 = tid & 31;
    const int p = pad[n];

    float4 q = make_float4(0.f, 0.f, 0.f, 0.f);
    float s = 0.f;
    if (!p) {
        int id = ws_ids[n * NG + g];
        q = ((const float4*)(cb + ((size_t)id * NG + g) * ND))[d4];
        float4 a = ((const float4*)(x + (size_t)n * (NG * ND)))[tid];
        float e0 = q.x - a.x, e1 = q.y - a.y, e2 = q.z - a.z, e3 = q.w - a.w;
        s = e0 * e0 + e1 * e1 + e2 * e2 + e3 * e3;
    }
    ((float4*)(out_q + (size_t)n * (NG * ND)))[tid] = q;

    for (int off = 32; off > 0; off >>= 1) s += __shfl_down(s, off);
    __shared__ float red[4];
    int w = tid >> 6, lane = tid & 63;
    if (lane == 0) red[w] = s;
    __syncthreads();
    if (tid == 0) ws_loss[n] = (red[0] + red[1]) + (red[2] + red[3]);
}

// ---------------------------------------------------------------------------
__global__ __launch_bounds__(256) void final_kernel(
    const int* __restrict__ pad, const float* __restrict__ ws_loss,
    float* __restrict__ out_l) {
    __shared__ float sr[256];
    __shared__ int mr[256];
    const int tid = threadIdx.x;
    float s = 0.f;
    int m = 0;
    for (int i = tid; i < BT; i += 256) {
        s += ws_loss[i];
        m += 1 - pad[i];
    }
    sr[tid] = s;
    mr[tid] = m;
    __syncthreads();
    for (int st = 128; st > 0; st >>= 1) {
        if (tid < st) { sr[tid] += sr[tid + st]; mr[tid] += mr[tid + st]; }
        __syncthreads();
    }
    if (tid == 0) {
        float k = sr[0] / (float)mr[0];
        out_l[0] = k;
        out_l[1] = k;
        out_l[2] = k + k;
    }
}

// ---------------------------------------------------------------------------
extern "C" void kernel_launch(void* const* d_in, const int* in_sizes, int n_in,
                              void* d_out, int out_size, void* d_ws, size_t ws_size,
                              hipStream_t stream) {
    const float* x = (const float*)d_in[0];
    const int* pad = (const int*)d_in[1];
    const float* cb = (const float*)d_in[2];
    float* out = (float*)d_out;
    float* ws = (float*)d_ws;

    float* ws_c2a = ws + OFF_C2A;
    float* ws_c2b = ws + OFF_C2B;
    int* ws_ids = (int*)(ws + OFF_IDS);
    float* ws_loss = ws + OFF_LOSS;
    int* ws_cnt = (int*)(ws + OFF_CNT);
    int* ws_flags = (int*)(ws + OFF_FLAGS);
    f16* cbh = (f16*)(ws + OFF_CBH);
    f16* cbl = (f16*)(ws + OFF_CBL);

    hipMemsetAsync(ws_cnt, 0, 4, stream);
    prep_kernel<<<NV * NG / 256, 256, 0, stream>>>(cb, cbh, cbl, ws_c2a, ws_c2b,
                                                   ws_cnt);
    mfma_gemm<<<(BT / BM) * NG, 256, 0, stream>>>(x, cbh, cbl, ws_c2b, pad,
                                                  ws_ids, out + OUT_IDS, ws_cnt,
                                                  ws_flags);
    recheck<<<2048, 256, 0, stream>>>(x, pad, cb, ws_c2a, ws_cnt, ws_flags,
                                      ws_ids, out + OUT_IDS);
    gather_kernel<<<BT, 256, 0, stream>>>(x, pad, cb, ws_ids, out + OUT_Q, ws_loss);
    final_kernel<<<1, 256, 0, stream>>>(pad, ws_loss, out + OUT_L);
}